// Round 1
// baseline (336.153 us; speedup 1.0000x reference)
//
#include <hip/hip_runtime.h>
#include <math.h>

#define LOG2E 1.4426950408889634f
#define LN2   0.6931471805599453

// ---------------- Kernel A: first-occurrence flags + exclusive prefix YZ ----
__global__ __launch_bounds__(256) void prep_kernel(
    const int* __restrict__ y, const float* __restrict__ yts,
    int S, float* __restrict__ yz_excl, int* __restrict__ isfirst_g)
{
    __shared__ int   sy[2048];
    __shared__ float val[2048];
    __shared__ float part[256];
    const int tid = threadIdx.x;

    for (int j = tid; j < S; j += 256) sy[j] = y[j];
    __syncthreads();

    // isfirst[j]: token y[j] did not appear at any i<j.
    // Inner loop reads sy[i] at the same i across lanes -> LDS broadcast (free).
    for (int j = tid; j < S; j += 256) {
        const int t = sy[j];
        int first = 1;
        for (int i = 0; i < j; ++i) {
            if (sy[i] == t) { first = 0; break; }
        }
        isfirst_g[j] = first;
        val[j] = first ? yts[t] : 0.0f;
    }
    __syncthreads();

    // exclusive scan of val -> yz_excl (chunked + Hillis-Steele over partials)
    const int CH = (S + 255) / 256;
    const int lo = tid * CH;
    const int hi = min(lo + CH, S);
    float p = 0.0f;
    for (int j = lo; j < hi; ++j) p += val[j];
    part[tid] = p;
    __syncthreads();
    for (int off = 1; off < 256; off <<= 1) {
        float v = (tid >= off) ? part[tid - off] : 0.0f;
        __syncthreads();
        part[tid] += v;
        __syncthreads();
    }
    float run = (tid > 0) ? part[tid - 1] : 0.0f;
    for (int j = lo; j < hi; ++j) { yz_excl[j] = run; run += val[j]; }
}

// ---------------- Kernel B: per-row logsumexp + weighted sum + gather -------
__global__ __launch_bounds__(256) void row_kernel(
    const float* __restrict__ x, const float* __restrict__ yts,
    const int* __restrict__ y, const int* __restrict__ isfirst,
    int S, int V,
    float* __restrict__ lse_g, float* __restrict__ wsum_g, float* __restrict__ G_g)
{
    const int row = blockIdx.x;
    const int tid = threadIdx.x;
    const float* __restrict__ xr = x + (size_t)row * (size_t)V;

    // online (base-2) max / sum-exp + weighted plain sum
    float m = -1.0e30f;   // finite sentinel: avoids (-inf)-(-inf) NaN in merges
    float se = 0.0f;
    float ws = 0.0f;

    const int nvec = V >> 2;
    const float4* __restrict__ x4 = (const float4*)xr;
    const float4* __restrict__ y4 = (const float4*)yts;

    for (int i = tid; i < nvec; i += 256) {
        const float4 xv = x4[i];
        const float4 yv = y4[i];
        float u, nm;
        u = xv.x * LOG2E; nm = fmaxf(m, u); se = se * exp2f(m - nm) + exp2f(u - nm); m = nm; ws = fmaf(yv.x, xv.x, ws);
        u = xv.y * LOG2E; nm = fmaxf(m, u); se = se * exp2f(m - nm) + exp2f(u - nm); m = nm; ws = fmaf(yv.y, xv.y, ws);
        u = xv.z * LOG2E; nm = fmaxf(m, u); se = se * exp2f(m - nm) + exp2f(u - nm); m = nm; ws = fmaf(yv.z, xv.z, ws);
        u = xv.w * LOG2E; nm = fmaxf(m, u); se = se * exp2f(m - nm) + exp2f(u - nm); m = nm; ws = fmaf(yv.w, xv.w, ws);
    }
    for (int i = (nvec << 2) + tid; i < V; i += 256) {   // tail (V%4)
        const float xv = xr[i];
        const float u = xv * LOG2E;
        const float nm = fmaxf(m, u);
        se = se * exp2f(m - nm) + exp2f(u - nm); m = nm;
        ws = fmaf(yts[i], xv, ws);
    }

    // wave reduce (64 lanes)
    #pragma unroll
    for (int off = 1; off < 64; off <<= 1) {
        const float m2 = __shfl_xor(m, off);
        const float s2 = __shfl_xor(se, off);
        const float nm = fmaxf(m, m2);
        se = se * exp2f(m - nm) + s2 * exp2f(m2 - nm);
        m = nm;
        ws += __shfl_xor(ws, off);
    }

    __shared__ float sm[4], ss[4], sw[4], sg[4];
    const int wid = tid >> 6, lane = tid & 63;
    if (lane == 0) { sm[wid] = m; ss[wid] = se; sw[wid] = ws; }
    __syncthreads();
    if (tid == 0) {
        for (int w2 = 1; w2 < 4; ++w2) {
            const float m2 = sm[w2], s2 = ss[w2];
            const float nm = fmaxf(m, m2);
            se = se * exp2f(m - nm) + s2 * exp2f(m2 - nm);
            m = nm;
            ws += sw[w2];
        }
        lse_g[row]  = (float)(LN2 * ((double)m + (double)log2f(se)));
        wsum_g[row] = ws;
    }

    // gather: G_row = sum over first-occurrence steps j<row of yts[t]*x[row,t]
    float g = 0.0f;
    for (int j = tid; j < row; j += 256) {
        if (isfirst[j]) {
            const int t = y[j];
            g += yts[t] * xr[t];   // row is L1/L2-hot after streaming pass
        }
    }
    #pragma unroll
    for (int off = 1; off < 64; off <<= 1) g += __shfl_xor(g, off);
    if (lane == 0) sg[wid] = g;
    __syncthreads();
    if (tid == 0) G_g[row] = sg[0] + sg[1] + sg[2] + sg[3];
}

// ---------------- Kernel C: combine (f64) -----------------------------------
__global__ __launch_bounds__(256) void combine_kernel(
    const float* __restrict__ zm, const float* __restrict__ zs,
    const float* __restrict__ yts,
    const float* __restrict__ lse, const float* __restrict__ wsum,
    const float* __restrict__ G, const float* __restrict__ yz,
    int L, int S, int V, float* __restrict__ out)
{
    const int tid = threadIdx.x;
    __shared__ double sd[256];

    // W = sum(yts)
    double acc = 0.0;
    for (int v = tid; v < V; v += 256) acc += (double)yts[v];
    sd[tid] = acc; __syncthreads();
    for (int off = 128; off; off >>= 1) { if (tid < off) sd[tid] += sd[tid + off]; __syncthreads(); }
    const double W = sd[0];
    __syncthreads();

    // KLD
    acc = 0.0;
    for (int i = tid; i < L; i += 256) {
        const double mq = (double)zm[i] * (double)zm[i];
        const double sq = (double)zs[i] * (double)zs[i];
        acc += mq + sq - log(sq) - 1.0;
    }
    sd[tid] = acc; __syncthreads();
    for (int off = 128; off; off >>= 1) { if (tid < off) sd[tid] += sd[tid + off]; __syncthreads(); }
    const double kld = sd[0] / (double)L;
    __syncthreads();

    // likelihood = sum_s -w_s * [ (wsum_s - W*lse_s) - (G_s - YZ_s*lse_s) ]
    acc = 0.0;
    for (int s = tid; s < S; s += 256) {
        const double l = (double)lse[s];
        const double sumy = ((double)wsum[s] - W * l) - ((double)G[s] - (double)yz[s] * l);
        acc += -sumy / (double)(S - s);
    }
    sd[tid] = acc; __syncthreads();
    for (int off = 128; off; off >>= 1) { if (tid < off) sd[tid] += sd[tid + off]; __syncthreads(); }

    if (tid == 0) out[0] = (float)(0.1 * kld + sd[0] / (double)S);
}

// ---------------- launch -----------------------------------------------------
extern "C" void kernel_launch(void* const* d_in, const int* in_sizes, int n_in,
                              void* d_out, int out_size, void* d_ws, size_t ws_size,
                              hipStream_t stream)
{
    const float* x   = (const float*)d_in[0];   // decoder_output [1,S,V] f32
    const float* zm  = (const float*)d_in[1];   // z_mean [1,L]
    const float* zs  = (const float*)d_in[2];   // z_sigma [1,L]
    const int*   y   = (const int*)d_in[3];     // y_true [1,S] int32
    const float* yts = (const float*)d_in[4];   // y_true_s [1,V]
    float* out = (float*)d_out;

    const int L = in_sizes[1];
    const int S = in_sizes[3];
    const int V = in_sizes[4];

    float* lse     = (float*)d_ws;
    float* wsum    = lse + S;
    float* G       = wsum + S;
    float* yz      = G + S;
    int*   isfirst = (int*)(yz + S);

    prep_kernel<<<1, 256, 0, stream>>>(y, yts, S, yz, isfirst);
    row_kernel<<<S, 256, 0, stream>>>(x, yts, y, isfirst, S, V, lse, wsum, G);
    combine_kernel<<<1, 256, 0, stream>>>(zm, zs, yts, lse, wsum, G, yz, L, S, V, out);
}

// Round 2
// 102.891 us; speedup vs baseline: 3.2671x; 3.2671x over previous
//
#include <hip/hip_runtime.h>
#include <math.h>

#define LOG2E 1.4426950408889634f
#define LN2   0.6931471805599453

// ---------------- Kernel A: first-occurrence flags (wave-parallel) ----------
// isfirst[j] = 1 iff token y[j] does not appear at any i<j.
// One wave per j; 64 lanes scan i<j in stride-64; __any ballot combines.
__global__ __launch_bounds__(256) void prep_kernel(
    const int* __restrict__ y, int S, int* __restrict__ isfirst_g)
{
    __shared__ int sy[2048];
    const int tid = threadIdx.x;
    for (int j = tid; j < S; j += 256) sy[j] = y[j];
    __syncthreads();

    const int lane = tid & 63, wid = tid >> 6;
    const int gw = blockIdx.x * 4 + wid;      // global wave id
    const int nw = gridDim.x * 4;             // total waves
    for (int j = gw; j < S; j += nw) {
        const int t = sy[j];                  // uniform per wave -> broadcast
        int found = 0;
        for (int i = lane; i < j; i += 64) found |= (sy[i] == t);
        const int fl = __any(found) ? 0 : 1;
        if (lane == 0) isfirst_g[j] = fl;
    }
}

// ---------------- Kernel B: per-row logsumexp + weighted sum + gather -------
__global__ __launch_bounds__(256) void row_kernel(
    const float* __restrict__ x, const float* __restrict__ yts,
    const int* __restrict__ y, const int* __restrict__ isfirst,
    int S, int V,
    float* __restrict__ lse_g, float* __restrict__ wsum_g,
    float* __restrict__ G_g, float* __restrict__ yz_g)
{
    const int row = blockIdx.x;
    const int tid = threadIdx.x;
    const float* __restrict__ xr = x + (size_t)row * (size_t)V;

    // 4 independent online (base-2) max/sum-exp chains + weighted sums (ILP)
    float m0 = -1.0e30f, m1 = -1.0e30f, m2 = -1.0e30f, m3 = -1.0e30f;
    float s0 = 0.f, s1 = 0.f, s2 = 0.f, s3 = 0.f;
    float w0 = 0.f, w1 = 0.f, w2 = 0.f, w3 = 0.f;

    const int nvec = V >> 2;
    const float4* __restrict__ x4 = (const float4*)xr;
    const float4* __restrict__ y4 = (const float4*)yts;

    for (int i = tid; i < nvec; i += 256) {
        const float4 xv = x4[i];
        const float4 yv = y4[i];
        float u, nm;
        u = xv.x * LOG2E; nm = fmaxf(m0, u); s0 = s0 * exp2f(m0 - nm) + exp2f(u - nm); m0 = nm; w0 = fmaf(yv.x, xv.x, w0);
        u = xv.y * LOG2E; nm = fmaxf(m1, u); s1 = s1 * exp2f(m1 - nm) + exp2f(u - nm); m1 = nm; w1 = fmaf(yv.y, xv.y, w1);
        u = xv.z * LOG2E; nm = fmaxf(m2, u); s2 = s2 * exp2f(m2 - nm) + exp2f(u - nm); m2 = nm; w2 = fmaf(yv.z, xv.z, w2);
        u = xv.w * LOG2E; nm = fmaxf(m3, u); s3 = s3 * exp2f(m3 - nm) + exp2f(u - nm); m3 = nm; w3 = fmaf(yv.w, xv.w, w3);
    }
    for (int i = (nvec << 2) + tid; i < V; i += 256) {   // tail (V%4)
        const float xv = xr[i];
        const float u = xv * LOG2E;
        const float nm = fmaxf(m0, u);
        s0 = s0 * exp2f(m0 - nm) + exp2f(u - nm); m0 = nm;
        w0 = fmaf(yts[i], xv, w0);
    }

    // merge 4 chains
    float m = m0, se = s0;
    {
        float nm;
        nm = fmaxf(m, m1); se = se * exp2f(m - nm) + s1 * exp2f(m1 - nm); m = nm;
        nm = fmaxf(m, m2); se = se * exp2f(m - nm) + s2 * exp2f(m2 - nm); m = nm;
        nm = fmaxf(m, m3); se = se * exp2f(m - nm) + s3 * exp2f(m3 - nm); m = nm;
    }
    float ws = (w0 + w1) + (w2 + w3);

    // wave reduce (64 lanes)
    #pragma unroll
    for (int off = 1; off < 64; off <<= 1) {
        const float m2_ = __shfl_xor(m, off);
        const float s2_ = __shfl_xor(se, off);
        const float nm = fmaxf(m, m2_);
        se = se * exp2f(m - nm) + s2_ * exp2f(m2_ - nm);
        m = nm;
        ws += __shfl_xor(ws, off);
    }

    __shared__ float sm[4], ss[4], sw[4], sg[4], sz[4];
    const int wid = tid >> 6, lane = tid & 63;
    if (lane == 0) { sm[wid] = m; ss[wid] = se; sw[wid] = ws; }
    __syncthreads();
    if (tid == 0) {
        for (int w2_ = 1; w2_ < 4; ++w2_) {
            const float m2_ = sm[w2_], s2_ = ss[w2_];
            const float nm = fmaxf(m, m2_);
            se = se * exp2f(m - nm) + s2_ * exp2f(m2_ - nm);
            m = nm;
            ws += sw[w2_];
        }
        lse_g[row]  = (float)(LN2 * ((double)m + (double)log2f(se)));
        wsum_g[row] = ws;
    }

    // gather: over first-occurrence steps j<row:
    //   G_row  += yts[t]*x[row,t]   (row is L2-hot after the streaming pass)
    //   YZ_row += yts[t]            (replaces the old prefix scan)
    float g = 0.0f, yzv = 0.0f;
    for (int j = tid; j < row; j += 256) {
        if (isfirst[j]) {
            const int t = y[j];
            const float yv = yts[t];
            g   += yv * xr[t];
            yzv += yv;
        }
    }
    #pragma unroll
    for (int off = 1; off < 64; off <<= 1) {
        g   += __shfl_xor(g, off);
        yzv += __shfl_xor(yzv, off);
    }
    if (lane == 0) { sg[wid] = g; sz[wid] = yzv; }
    __syncthreads();
    if (tid == 0) {
        G_g[row]  = sg[0] + sg[1] + sg[2] + sg[3];
        yz_g[row] = sz[0] + sz[1] + sz[2] + sz[3];
    }
}

// ---------------- Kernel C: combine (f64) -----------------------------------
__global__ __launch_bounds__(256) void combine_kernel(
    const float* __restrict__ zm, const float* __restrict__ zs,
    const float* __restrict__ yts,
    const float* __restrict__ lse, const float* __restrict__ wsum,
    const float* __restrict__ G, const float* __restrict__ yz,
    int L, int S, int V, float* __restrict__ out)
{
    const int tid = threadIdx.x;
    __shared__ double sd[256];

    // W = sum(yts)
    double acc = 0.0;
    for (int v = tid; v < V; v += 256) acc += (double)yts[v];
    sd[tid] = acc; __syncthreads();
    for (int off = 128; off; off >>= 1) { if (tid < off) sd[tid] += sd[tid + off]; __syncthreads(); }
    const double W = sd[0];
    __syncthreads();

    // KLD
    acc = 0.0;
    for (int i = tid; i < L; i += 256) {
        const double mq = (double)zm[i] * (double)zm[i];
        const double sq = (double)zs[i] * (double)zs[i];
        acc += mq + sq - log(sq) - 1.0;
    }
    sd[tid] = acc; __syncthreads();
    for (int off = 128; off; off >>= 1) { if (tid < off) sd[tid] += sd[tid + off]; __syncthreads(); }
    const double kld = sd[0] / (double)L;
    __syncthreads();

    // likelihood = sum_s -w_s * [ (wsum_s - W*lse_s) - (G_s - YZ_s*lse_s) ]
    acc = 0.0;
    for (int s = tid; s < S; s += 256) {
        const double l = (double)lse[s];
        const double sumy = ((double)wsum[s] - W * l) - ((double)G[s] - (double)yz[s] * l);
        acc += -sumy / (double)(S - s);
    }
    sd[tid] = acc; __syncthreads();
    for (int off = 128; off; off >>= 1) { if (tid < off) sd[tid] += sd[tid + off]; __syncthreads(); }

    if (tid == 0) out[0] = (float)(0.1 * kld + sd[0] / (double)S);
}

// ---------------- launch -----------------------------------------------------
extern "C" void kernel_launch(void* const* d_in, const int* in_sizes, int n_in,
                              void* d_out, int out_size, void* d_ws, size_t ws_size,
                              hipStream_t stream)
{
    const float* x   = (const float*)d_in[0];   // decoder_output [1,S,V] f32
    const float* zm  = (const float*)d_in[1];   // z_mean [1,L]
    const float* zs  = (const float*)d_in[2];   // z_sigma [1,L]
    const int*   y   = (const int*)d_in[3];     // y_true [1,S] int32
    const float* yts = (const float*)d_in[4];   // y_true_s [1,V]
    float* out = (float*)d_out;

    const int L = in_sizes[1];
    const int S = in_sizes[3];
    const int V = in_sizes[4];

    float* lse     = (float*)d_ws;
    float* wsum    = lse + S;
    float* G       = wsum + S;
    float* yz      = G + S;
    int*   isfirst = (int*)(yz + S);

    prep_kernel<<<16, 256, 0, stream>>>(y, S, isfirst);
    row_kernel<<<S, 256, 0, stream>>>(x, yts, y, isfirst, S, V, lse, wsum, G, yz);
    combine_kernel<<<1, 256, 0, stream>>>(zm, zs, yts, lse, wsum, G, yz, L, S, V, out);
}